// Round 3
// baseline (635.371 us; speedup 1.0000x reference)
//
#include <hip/hip_runtime.h>
#include <cstdint>
#include <cstddef>

#define TT 1000
#define NB 64000  // B*T

// async global->LDS DMA, 16 B per lane. lds dest must be wave-uniform base;
// lane i lands at base + i*16.
__device__ __forceinline__ void gload16(const float* g, float* l) {
  __builtin_amdgcn_global_load_lds(
      (const __attribute__((address_space(1))) unsigned int*)g,
      (__attribute__((address_space(3))) unsigned int*)l, 16, 0, 0);
}

// ---------------------------------------------------------------------------
// gemm: Z[n,o] = sum_k Wt[k][o] * S[n][k]
// S: [N,K] u8 (0/1); Wt: [K,Wld] f32 pre-transposed; Z: [N,Zld] f32.
// 128n x 128o tile, BK=16, 256 thr, 8x8/thread. Double-buffered LDS with
// zero-VGPR async B prefetch (global_load_lds) + 2-VGPR A prefetch.
// One barrier per k-tile. Accumulation: ascending-k fmaf chain (bit-exact
// vs r1 which matched the reference with absmax 0).
// ---------------------------------------------------------------------------
__global__ __launch_bounds__(256) void gemm128(
    const uint8_t* __restrict__ S, const float* __restrict__ Wt,
    float* __restrict__ Z, int K, int Wld, int Zld, int Ostore) {
  __shared__ __align__(16) float As[2][16][128];
  __shared__ __align__(16) float Bs[2][16 * 128];
  const int t = threadIdx.x;
  const int bn = blockIdx.x * 128;
  const int bo = blockIdx.y * 128;
  const int tx4 = (t & 15) * 4;
  const int ty4 = ((t >> 4) & 15) * 4;
  const int srow = t >> 1;      // A-staging row 0..127
  const int skq = (t & 1) * 8;  // 0 or 8

  // B staging geometry: flat 2048-float tile, thread t covers bf0 and bf1
  const int bf0 = t * 4;
  const int bf1 = 1024 + t * 4;
  const int bk0 = bf0 >> 7, bc0 = bf0 & 127;
  const int bk1 = bf1 >> 7, bc1 = bf1 & 127;
  const int wbase = (t >> 6) << 8;  // wave-uniform float offset into Bs half

  float acc[8][8];
#pragma unroll
  for (int j = 0; j < 8; j++)
#pragma unroll
    for (int i = 0; i < 8; i++) acc[j][i] = 0.f;

  const int ntiles = K >> 4;
  const uint8_t* sprow = S + (size_t)(bn + srow) * K;

  // prologue: stage tile 0 (B via DMA, A via registers)
  gload16(Wt + (size_t)bk0 * Wld + bo + bc0, &Bs[0][0] + wbase);
  gload16(Wt + (size_t)bk1 * Wld + bo + bc1, &Bs[0][1024] + wbase);
  {
    uint2 av = *(const uint2*)(sprow + skq);
#pragma unroll
    for (int j = 0; j < 4; j++)
      As[0][skq + j][srow] = (float)((av.x >> (8 * j)) & 0xffu);
#pragma unroll
    for (int j = 0; j < 4; j++)
      As[0][skq + 4 + j][srow] = (float)((av.y >> (8 * j)) & 0xffu);
  }
  __syncthreads();  // drains DMA (vmcnt) + barrier

  for (int tile = 0; tile < ntiles; tile++) {
    const int cur = tile & 1, nxt = cur ^ 1;
    const int k1 = (tile + 1) << 4;
    const bool more = (tile + 1 < ntiles);
    uint2 av;
    if (more) {
      // async B prefetch straight to LDS (no VGPR cost), A to 2 VGPRs
      gload16(Wt + (size_t)(k1 + bk0) * Wld + bo + bc0, &Bs[nxt][0] + wbase);
      gload16(Wt + (size_t)(k1 + bk1) * Wld + bo + bc1,
              &Bs[nxt][1024] + wbase);
      av = *(const uint2*)(sprow + k1 + skq);
    }
#pragma unroll
    for (int kk = 0; kk < 16; kk++) {
      float4 a0 = *(const float4*)&As[cur][kk][ty4];
      float4 a1 = *(const float4*)&As[cur][kk][64 + ty4];
      float4 b0 = *(const float4*)&Bs[cur][kk * 128 + tx4];
      float4 b1 = *(const float4*)&Bs[cur][kk * 128 + 64 + tx4];
      float avv[8] = {a0.x, a0.y, a0.z, a0.w, a1.x, a1.y, a1.z, a1.w};
      float bvv[8] = {b0.x, b0.y, b0.z, b0.w, b1.x, b1.y, b1.z, b1.w};
#pragma unroll
      for (int j = 0; j < 8; j++)
#pragma unroll
        for (int i = 0; i < 8; i++)
          acc[j][i] = fmaf(avv[j], bvv[i], acc[j][i]);
    }
    if (more) {
#pragma unroll
      for (int j = 0; j < 4; j++)
        As[nxt][skq + j][srow] = (float)((av.x >> (8 * j)) & 0xffu);
#pragma unroll
      for (int j = 0; j < 4; j++)
        As[nxt][skq + 4 + j][srow] = (float)((av.y >> (8 * j)) & 0xffu);
    }
    __syncthreads();
  }

  // store (N multiple of 128; o guarded vs Ostore)
#pragma unroll
  for (int jp = 0; jp < 2; jp++) {
#pragma unroll
    for (int j = 0; j < 4; j++) {
      int n = bn + jp * 64 + ty4 + j;
#pragma unroll
      for (int ip = 0; ip < 2; ip++) {
        int o0 = bo + ip * 64 + tx4;
        const float* a = &acc[jp * 4 + j][ip * 4];
        float* zp = Z + (size_t)n * Zld + o0;
        if (o0 + 3 < Ostore) {
          *(float4*)zp = make_float4(a[0], a[1], a[2], a[3]);
        } else {
#pragma unroll
          for (int i = 0; i < 4; i++)
            if (o0 + i < Ostore) zp[i] = a[i];
        }
      }
    }
  }
}

// ---------------------------------------------------------------------------
// CUBA LIF recurrence: depth-4 x U=25 load pipeline (3-batch slack ~= HBM
// latency). Exact per-step fp32 mul/add chain (unchanged from r1/r2).
// ---------------------------------------------------------------------------
template <bool FINAL>
__global__ __launch_bounds__(64) void cuba_kernel(
    const float* __restrict__ Z, uint8_t* __restrict__ Sout,
    float* __restrict__ Fout, unsigned int* __restrict__ cnt, int O,
    int total) {
  int gid = blockIdx.x * 64 + threadIdx.x;
  unsigned int c = 0;
  if (gid < total) {
    int b = gid / O;
    int o = gid - b * O;
    const float* zp = Z + (size_t)b * TT * O + o;
    uint8_t* sp = Sout + (size_t)b * TT * O + o;
    float* fp = Fout + ((size_t)b * O + o) * TT;
    float cur = 0.f, volt = 0.f;
    constexpr int U = 25;  // TT = 1000 = 40 batches = 10 outer x 4
    float z0[U], z1[U], z2[U], z3[U];

#define LOADB(buf, tbase)                          \
  _Pragma("unroll") for (int u = 0; u < U; u++) {  \
    buf[u] = zp[(size_t)((tbase) + u) * O];        \
  }
#define COMPB(buf, tbase)                                   \
  _Pragma("unroll") for (int u = 0; u < U; u++) {           \
    cur = __fadd_rn(__fmul_rn(0.75f, cur), buf[u]);         \
    volt = __fadd_rn(__fmul_rn(0.97f, volt), cur);          \
    bool fire = volt >= 1.25f;                              \
    volt = fire ? 0.f : volt;                               \
    c += fire ? 1u : 0u;                                    \
    if (FINAL)                                              \
      fp[(tbase) + u] = fire ? 1.f : 0.f;                   \
    else                                                    \
      sp[(size_t)((tbase) + u) * O] = (uint8_t)(fire ? 1 : 0); \
  }

    LOADB(z0, 0)
    LOADB(z1, U)
    LOADB(z2, 2 * U)
    for (int i = 0; i < 10; i++) {
      const int base = i * 4 * U;
      LOADB(z3, base + 3 * U)
      COMPB(z0, base)
      if (i < 9) LOADB(z0, base + 4 * U)
      COMPB(z1, base + U)
      if (i < 9) LOADB(z1, base + 5 * U)
      COMPB(z2, base + 2 * U)
      if (i < 9) LOADB(z2, base + 6 * U)
      COMPB(z3, base + 3 * U)
    }
#undef LOADB
#undef COMPB
  }
#pragma unroll
  for (int off = 32; off; off >>= 1) c += __shfl_down(c, off, 64);
  if ((threadIdx.x & 63) == 0) atomicAdd(cnt, c);
}

// ---------------------------------------------------------------------------
// Input: [B,20,T] f32 -> [B*T, 32] u8 (K zero-padded)
// ---------------------------------------------------------------------------
__global__ __launch_bounds__(256) void prep_input(const float* __restrict__ X,
                                                  uint8_t* __restrict__ Sp) {
  int gid = blockIdx.x * 256 + threadIdx.x;
  if (gid >= NB) return;
  int b = gid / TT, tt = gid - b * TT;
  unsigned int w[8];
#pragma unroll
  for (int i = 0; i < 8; i++) w[i] = 0u;
#pragma unroll
  for (int c = 0; c < 20; c++) {
    float v = X[((size_t)b * 20 + c) * TT + tt];
    unsigned int bit = (v != 0.f) ? 1u : 0u;
    w[c >> 2] |= bit << ((c & 3) * 8);
  }
  uint4* dst = (uint4*)(Sp + (size_t)gid * 32);
  dst[0] = make_uint4(w[0], w[1], w[2], w[3]);
  dst[1] = make_uint4(w[4], w[5], w[6], w[7]);
}

// W [O,K] -> Wt [Kpad,Opad] transposed + zero-padded
__global__ __launch_bounds__(256) void prep_w(const float* __restrict__ W,
                                              float* __restrict__ Wt, int O,
                                              int K, int Kpad, int Opad) {
  int i = blockIdx.x * 256 + threadIdx.x;
  if (i >= Kpad * Opad) return;
  int k = i / Opad, o = i - k * Opad;
  Wt[i] = (k < K && o < O) ? W[(size_t)o * K + k] : 0.f;
}

__global__ void finalize_counts(const unsigned int* __restrict__ cnt,
                                float* __restrict__ out) {
  int i = threadIdx.x;
  if (i < 4) {
    const float denom[4] = {16384000.f, 16384000.f, 16384000.f, 2240000.f};
    out[i] = (float)cnt[i] / denom[i];
  }
}

// ---------------------------------------------------------------------------
extern "C" void kernel_launch(void* const* d_in, const int* in_sizes, int n_in,
                              void* d_out, int out_size, void* d_ws,
                              size_t ws_size, hipStream_t stream) {
  const float* X = (const float*)d_in[0];
  const float* W1 = (const float*)d_in[1];
  const float* W2 = (const float*)d_in[2];
  const float* W3 = (const float*)d_in[3];
  const float* W4 = (const float*)d_in[4];
  float* out = (float*)d_out;

  char* ws = (char*)d_ws;
  unsigned int* cnt = (unsigned int*)ws;             // 256 B
  float* Z = (float*)(ws + 256);                     // 65,536,000
  uint8_t* Sa = (uint8_t*)(ws + 256 + 65536000ull);  // 16,384,000
  uint8_t* Sb = Sa + 16384000ull;                    // 16,384,000
  uint8_t* Sin = Sb + 16384000ull;                   // 2,048,000
  float* Wt1 = (float*)(Sin + 2048000ull);           // 32*256*4
  float* Wt2 = Wt1 + 32 * 256;                       // 256*256*4
  float* Wt3 = Wt2 + 256 * 256;                      // 256*256*4
  float* Wt4 = Wt3 + 256 * 256;                      // 256*128*4

  hipMemsetAsync(cnt, 0, 16, stream);
  prep_w<<<(32 * 256 + 255) / 256, 256, 0, stream>>>(W1, Wt1, 256, 20, 32, 256);
  prep_w<<<(256 * 256) / 256, 256, 0, stream>>>(W2, Wt2, 256, 256, 256, 256);
  prep_w<<<(256 * 256) / 256, 256, 0, stream>>>(W3, Wt3, 256, 256, 256, 256);
  prep_w<<<(256 * 128) / 256, 256, 0, stream>>>(W4, Wt4, 35, 256, 256, 128);
  prep_input<<<(NB + 255) / 256, 256, 0, stream>>>(X, Sin);

  dim3 gBig(NB / 128, 2);
  dim3 gOut(NB / 128, 1);

  gemm128<<<gBig, 256, 0, stream>>>(Sin, Wt1, Z, 32, 256, 256, 256);
  cuba_kernel<false><<<256, 64, 0, stream>>>(Z, Sa, nullptr, cnt + 0, 256,
                                             16384);
  gemm128<<<gBig, 256, 0, stream>>>(Sa, Wt2, Z, 256, 256, 256, 256);
  cuba_kernel<false><<<256, 64, 0, stream>>>(Z, Sb, nullptr, cnt + 1, 256,
                                             16384);
  gemm128<<<gBig, 256, 0, stream>>>(Sb, Wt3, Z, 256, 256, 256, 256);
  cuba_kernel<false><<<256, 64, 0, stream>>>(Z, Sa, nullptr, cnt + 2, 256,
                                             16384);
  gemm128<<<gOut, 256, 0, stream>>>(Sa, Wt4, Z, 256, 128, 35, 35);
  cuba_kernel<true><<<35, 64, 0, stream>>>(Z, nullptr, out, cnt + 3, 35, 2240);
  finalize_counts<<<1, 64, 0, stream>>>(cnt, out + 2240000);
}

// Round 5
// 503.679 us; speedup vs baseline: 1.2615x; 1.2615x over previous
//
#include <hip/hip_runtime.h>
#include <cstdint>
#include <cstddef>

#define TT 1000
#define NB 64000  // B*T

// ---------------------------------------------------------------------------
// gemm_nt: Z[n,o] = sum_k Wt[k][o] * S[n][k]
// S: [N,K] u8 (0/1); Wt: [K,Wld] f32 pre-transposed; Z: [N,Zld] f32.
// 64n x BO(128/64) tile, BK=16, 256 threads, 4xTW per thread, 2-barrier
// K-loop (no prefetch — occupancy hides latency: ~8 blocks/CU).
// NUMERICS CONTRACT: each output is ONE ascending-k fp32 fmaf chain =
// bit-identical to np BLAS sgemm (r1 verified absmax 0.0). Do not reorder.
// ---------------------------------------------------------------------------
template <int BO>
__global__ __launch_bounds__(256) void gemm_nt(const uint8_t* __restrict__ S,
                                               const float* __restrict__ Wt,
                                               float* __restrict__ Z, int K,
                                               int Wld, int Zld, int Ostore) {
  constexpr int TW = BO / 16;  // o per thread
  __shared__ __align__(16) float As[16][64];
  __shared__ __align__(16) float Bs[16][BO];
  const int t = threadIdx.x;
  const int bn = blockIdx.x * 64;
  const int bo = blockIdx.y * BO;
  const int ty4 = (t >> 4) * 4;
  const int ox = (t & 15) * TW;
  const int srow = t >> 2;      // 0..63
  const int skq = (t & 3) * 4;  // 0,4,8,12

  float acc[4][TW];
#pragma unroll
  for (int j = 0; j < 4; j++)
#pragma unroll
    for (int i = 0; i < TW; i++) acc[j][i] = 0.f;

  const uint8_t* sprow = S + (size_t)(bn + srow) * K + skq;

  for (int k0 = 0; k0 < K; k0 += 16) {
    // stage A: 64 rows x 16 k u8 -> float (4 B per thread)
    {
      unsigned int v = *(const unsigned int*)(sprow + k0);
#pragma unroll
      for (int j = 0; j < 4; j++)
        As[skq + j][srow] = (float)((v >> (8 * j)) & 0xffu);
    }
    // stage B: flat contiguous copy (coalesced, conflict-free)
#pragma unroll
    for (int h = 0; h < BO / 64; h++) {
      int bf = h * 1024 + t * 4;
      int bk = bf / BO, bc = bf % BO;
      *(float4*)&Bs[bk][bc] =
          *(const float4*)(Wt + (size_t)(k0 + bk) * Wld + bo + bc);
    }
    __syncthreads();
#pragma unroll
    for (int kk = 0; kk < 16; kk++) {
      float4 a = *(const float4*)&As[kk][ty4];
      float av[4] = {a.x, a.y, a.z, a.w};
      float bv[TW];
#pragma unroll
      for (int i = 0; i < TW; i += 4) {
        float4 b = *(const float4*)&Bs[kk][ox + i];
        bv[i] = b.x;
        bv[i + 1] = b.y;
        bv[i + 2] = b.z;
        bv[i + 3] = b.w;
      }
#pragma unroll
      for (int j = 0; j < 4; j++)
#pragma unroll
        for (int i = 0; i < TW; i++)
          acc[j][i] = fmaf(av[j], bv[i], acc[j][i]);
    }
    __syncthreads();
  }

  // store (N multiple of 64; o guarded vs Ostore)
#pragma unroll
  for (int j = 0; j < 4; j++) {
    int n = bn + ty4 + j;
#pragma unroll
    for (int i = 0; i < TW; i += 4) {
      int o0 = bo + ox + i;
      float* zp = Z + (size_t)n * Zld + o0;
      if (o0 + 3 < Ostore) {
        *(float4*)zp = make_float4(acc[j][i], acc[j][i + 1], acc[j][i + 2],
                                   acc[j][i + 3]);
      } else {
#pragma unroll
        for (int q = 0; q < 4; q++)
          if (o0 + q < Ostore) zp[q] = acc[j][i + q];
      }
    }
  }
}

// ---------------------------------------------------------------------------
// CUBA LIF recurrence: depth-4 x U=25 load pipeline. Exact per-step fp32
// mul/add chain (matches np op-by-op; r1-verified). u8 spike out [n][k].
// ---------------------------------------------------------------------------
template <bool FINAL>
__global__ __launch_bounds__(64) void cuba_kernel(
    const float* __restrict__ Z, uint8_t* __restrict__ Sout,
    float* __restrict__ Fout, unsigned int* __restrict__ cnt, int O,
    int total) {
  int gid = blockIdx.x * 64 + threadIdx.x;
  unsigned int c = 0;
  if (gid < total) {
    int b = gid / O;
    int o = gid - b * O;
    const float* zp = Z + (size_t)b * TT * O + o;
    uint8_t* sp = Sout + (size_t)b * TT * O + o;
    float* fp = Fout + ((size_t)b * O + o) * TT;
    float cur = 0.f, volt = 0.f;
    constexpr int U = 25;  // 1000 = 40 batches, 4-deep pipeline
    float z0[U], z1[U], z2[U], z3[U];

#define LOADB(buf, tbase)                         \
  _Pragma("unroll") for (int u = 0; u < U; u++) { \
    buf[u] = zp[(size_t)((tbase) + u) * O];       \
  }
#define COMPB(buf, tbase)                                         \
  _Pragma("unroll") for (int u = 0; u < U; u++) {                 \
    cur = __fadd_rn(__fmul_rn(0.75f, cur), buf[u]);               \
    volt = __fadd_rn(__fmul_rn(0.97f, volt), cur);                \
    bool fire = volt >= 1.25f;                                    \
    volt = fire ? 0.f : volt;                                     \
    c += fire ? 1u : 0u;                                          \
    if (FINAL)                                                    \
      fp[(tbase) + u] = fire ? 1.f : 0.f;                         \
    else                                                          \
      sp[(size_t)((tbase) + u) * O] = (uint8_t)(fire ? 1 : 0);    \
  }

    LOADB(z0, 0)
    LOADB(z1, U)
    LOADB(z2, 2 * U)
    for (int i = 0; i < 10; i++) {
      const int base = i * 4 * U;
      LOADB(z3, base + 3 * U)
      COMPB(z0, base)
      if (i < 9) LOADB(z0, base + 4 * U)
      COMPB(z1, base + U)
      if (i < 9) LOADB(z1, base + 5 * U)
      COMPB(z2, base + 2 * U)
      if (i < 9) LOADB(z2, base + 6 * U)
      COMPB(z3, base + 3 * U)
    }
#undef LOADB
#undef COMPB
  }
#pragma unroll
  for (int off = 32; off; off >>= 1) c += __shfl_down(c, off, 64);
  if ((threadIdx.x & 63) == 0) atomicAdd(cnt, c);
}

// ---------------------------------------------------------------------------
// Input: [B,20,T] f32 -> [B*T, 32] u8 (K zero-padded)
// ---------------------------------------------------------------------------
__global__ __launch_bounds__(256) void prep_input(const float* __restrict__ X,
                                                  uint8_t* __restrict__ Sp) {
  int gid = blockIdx.x * 256 + threadIdx.x;
  if (gid >= NB) return;
  int b = gid / TT, tt = gid - b * TT;
  unsigned int w[8];
#pragma unroll
  for (int i = 0; i < 8; i++) w[i] = 0u;
#pragma unroll
  for (int c = 0; c < 20; c++) {
    float v = X[((size_t)b * 20 + c) * TT + tt];
    unsigned int bit = (v != 0.f) ? 1u : 0u;
    w[c >> 2] |= bit << ((c & 3) * 8);
  }
  uint4* dst = (uint4*)(Sp + (size_t)gid * 32);
  dst[0] = make_uint4(w[0], w[1], w[2], w[3]);
  dst[1] = make_uint4(w[4], w[5], w[6], w[7]);
}

// W [O,K] -> Wt [Kpad,Opad] transposed + zero-padded (value-exact copy)
__global__ __launch_bounds__(256) void prep_w(const float* __restrict__ W,
                                              float* __restrict__ Wt, int O,
                                              int K, int Kpad, int Opad) {
  int i = blockIdx.x * 256 + threadIdx.x;
  if (i >= Kpad * Opad) return;
  int k = i / Opad, o = i - k * Opad;
  Wt[i] = (k < K && o < O) ? W[(size_t)o * K + k] : 0.f;
}

__global__ void finalize_counts(const unsigned int* __restrict__ cnt,
                                float* __restrict__ out) {
  int i = threadIdx.x;
  if (i < 4) {
    const float denom[4] = {16384000.f, 16384000.f, 16384000.f, 2240000.f};
    out[i] = (float)cnt[i] / denom[i];
  }
}

// ---------------------------------------------------------------------------
extern "C" void kernel_launch(void* const* d_in, const int* in_sizes, int n_in,
                              void* d_out, int out_size, void* d_ws,
                              size_t ws_size, hipStream_t stream) {
  const float* X = (const float*)d_in[0];
  const float* W1 = (const float*)d_in[1];
  const float* W2 = (const float*)d_in[2];
  const float* W3 = (const float*)d_in[3];
  const float* W4 = (const float*)d_in[4];
  float* out = (float*)d_out;

  char* ws = (char*)d_ws;
  unsigned int* cnt = (unsigned int*)ws;             // 256 B
  float* Z = (float*)(ws + 256);                     // 65,536,000
  uint8_t* Sa = (uint8_t*)(ws + 256 + 65536000ull);  // 16,384,000
  uint8_t* Sb = Sa + 16384000ull;                    // 16,384,000
  uint8_t* Sin = Sb + 16384000ull;                   // 2,048,000
  float* Wt1 = (float*)(Sin + 2048000ull);           // 32*256*4
  float* Wt2 = Wt1 + 32 * 256;                       // 256*256*4
  float* Wt3 = Wt2 + 256 * 256;                      // 256*256*4
  float* Wt4 = Wt3 + 256 * 256;                      // 256*64*4

  hipMemsetAsync(cnt, 0, 16, stream);
  prep_w<<<(32 * 256 + 255) / 256, 256, 0, stream>>>(W1, Wt1, 256, 20, 32, 256);
  prep_w<<<(256 * 256) / 256, 256, 0, stream>>>(W2, Wt2, 256, 256, 256, 256);
  prep_w<<<(256 * 256) / 256, 256, 0, stream>>>(W3, Wt3, 256, 256, 256, 256);
  prep_w<<<(256 * 64) / 256, 256, 0, stream>>>(W4, Wt4, 35, 256, 256, 64);
  prep_input<<<(NB + 255) / 256, 256, 0, stream>>>(X, Sin);

  dim3 gBig(NB / 64, 2);  // 2000 blocks
  dim3 gOut(NB / 64, 1);  // 1000 blocks

  gemm_nt<128><<<gBig, 256, 0, stream>>>(Sin, Wt1, Z, 32, 256, 256, 256);
  cuba_kernel<false><<<256, 64, 0, stream>>>(Z, Sa, nullptr, cnt + 0, 256,
                                             16384);
  gemm_nt<128><<<gBig, 256, 0, stream>>>(Sa, Wt2, Z, 256, 256, 256, 256);
  cuba_kernel<false><<<256, 64, 0, stream>>>(Z, Sb, nullptr, cnt + 1, 256,
                                             16384);
  gemm_nt<128><<<gBig, 256, 0, stream>>>(Sb, Wt3, Z, 256, 256, 256, 256);
  cuba_kernel<false><<<256, 64, 0, stream>>>(Z, Sa, nullptr, cnt + 2, 256,
                                             16384);
  gemm_nt<64><<<gOut, 256, 0, stream>>>(Sa, Wt4, Z, 256, 64, 35, 35);
  cuba_kernel<true><<<35, 64, 0, stream>>>(Z, nullptr, out, cnt + 3, 35, 2240);
  finalize_counts<<<1, 64, 0, stream>>>(cnt, out + 2240000);
}